// Round 5
// baseline (646.162 us; speedup 1.0000x reference)
//
#include <hip/hip_runtime.h>

#define NN 50000   // nodes
#define NE 800000  // edges
#define DD 256     // feature dim
#define NX 8       // experts
#define BM 128     // k_y rows per block
#define BN 128     // k_y cols per block

typedef short s8v __attribute__((ext_vector_type(8)));   // 8 x bf16 (as i16)
typedef float f4v __attribute__((ext_vector_type(4)));   // MFMA accumulator

#define AS1 __attribute__((address_space(1)))
#define AS3 __attribute__((address_space(3)))

static __device__ __forceinline__ unsigned short f2bf(float f) {
  unsigned u = __builtin_bit_cast(unsigned, f);
  u = (u + 0x7fffu + ((u >> 16) & 1u)) >> 16;  // RNE
  return (unsigned short)u;
}
static __device__ __forceinline__ float bf2f(unsigned short u) {
  return __builtin_bit_cast(float, (unsigned)u << 16);
}

// ---------------- fused prep: Wt transpose | x->bf16 + xg | deg histogram ----------------
// blocks [0,2048): Wt   [2048,14548): xb+xg   [14548,17673): deg
__global__ __launch_bounds__(256) void k_prep(
    const float* __restrict__ x, const float* __restrict__ Wg,
    const float* __restrict__ We, const int* __restrict__ ei,
    unsigned short* __restrict__ Wt, unsigned short* __restrict__ xb,
    float* __restrict__ xg, int* __restrict__ deg) {
  int b = blockIdx.x, t = threadIdx.x;
  if (b < 2048) {  // Wt[e][o][d] = bf16(We[e][d][o])
    int i = b * 256 + t;
    int e = i >> 16, rem = i & 0xffff, o = rem >> 8, d = rem & 255;
    Wt[i] = f2bf(We[(e << 16) + (d << 8) + o]);
  } else if (b < 14548) {  // xb = bf16(x); xg = x @ Wg (f32)
    int wv = t >> 6, lane = t & 63;
    int n = (b - 2048) * 4 + wv;
    float4 v = ((const float4*)x)[(size_t)n * 64 + lane];
    ushort4 bb;
    bb.x = f2bf(v.x); bb.y = f2bf(v.y); bb.z = f2bf(v.z); bb.w = f2bf(v.w);
    ((ushort4*)xb)[(size_t)n * 64 + lane] = bb;
    float p[NX];
#pragma unroll
    for (int e = 0; e < NX; e++) p[e] = 0.f;
    const float* wr = Wg + lane * 4 * NX;
    float av[4] = {v.x, v.y, v.z, v.w};
#pragma unroll
    for (int j = 0; j < 4; j++)
#pragma unroll
      for (int e = 0; e < NX; e++) p[e] = fmaf(av[j], wr[j * NX + e], p[e]);
#pragma unroll
    for (int off = 32; off > 0; off >>= 1)
#pragma unroll
      for (int e = 0; e < NX; e++) p[e] += __shfl_xor(p[e], off, 64);
    if (lane == 0) {
      float4* gp = (float4*)(xg + (size_t)n * NX);
      gp[0] = make_float4(p[0], p[1], p[2], p[3]);
      gp[1] = make_float4(p[4], p[5], p[6], p[7]);
    }
  } else {  // degree histogram over dst
    int e = (b - 14548) * 256 + t;
    if (e < NE) atomicAdd(&deg[ei[NE + e]], 1);
  }
}

// 49 blocks x 1024: per-block exclusive scan -> rowptr, block totals -> bsum
__global__ void k_scan1(const int* __restrict__ deg, int* __restrict__ rowptr,
                        int* __restrict__ bsum) {
  __shared__ int buf[2][1024];
  int t = threadIdx.x, base = blockIdx.x * 1024;
  int v = (base + t < NN) ? deg[base + t] : 0;
  buf[0][t] = v;
  int cur = 0;
  __syncthreads();
  for (int off = 1; off < 1024; off <<= 1) {
    int s = buf[cur][t];
    if (t >= off) s += buf[cur][t - off];
    buf[cur ^ 1][t] = s;
    cur ^= 1;
    __syncthreads();
  }
  if (base + t < NN) rowptr[base + t] = buf[cur][t] - v;
  if (t == 1023) bsum[blockIdx.x] = buf[cur][1023];
}

__global__ void k_scan2(const int* __restrict__ bsum, int* __restrict__ boff,
                        int* __restrict__ rowptr) {
  int l = threadIdx.x;
  int v = (l < 49) ? bsum[l] : 0;
  int s = v;
  for (int off = 1; off < 64; off <<= 1) {
    int o = __shfl_up(s, off, 64);
    if (l >= off) s += o;
  }
  if (l < 49) boff[l] = s - v;
  if (l == 0) rowptr[NN] = NE;
}

__global__ void k_scan3(int* __restrict__ rowptr, const int* __restrict__ boff,
                        int* __restrict__ cursor) {
  int i = blockIdx.x * 1024 + threadIdx.x;
  if (i < NN) {
    int r = rowptr[i] + boff[blockIdx.x];
    rowptr[i] = r;
    cursor[i] = r;
  }
}

__global__ void k_scatter(const int* __restrict__ ei, int* __restrict__ cursor,
                          int* __restrict__ csr) {
  int e = blockIdx.x * 256 + threadIdx.x;
  if (e < NE) {
    int s = ei[e];
    int d = ei[NE + e];
    int p = atomicAdd(&cursor[d], 1);
    csr[p] = s;
  }
}

// ---------------- fused aggregation + gate: LDS-staged gather (VGPR-free MLP) ----------------
// Per wave, per 16-edge batch: 8 global_load_lds instructions (2 rows each, 1 KB),
// one vmcnt(0) round-trip, then LDS reduce. Data never occupies VGPRs, so all
// 8 row-fetches stay in flight regardless of occupancy-driven regalloc.
__global__ __launch_bounds__(256) void k_agggate(
    const unsigned short* __restrict__ xb, const float* __restrict__ xg,
    const int* __restrict__ rowptr, const int* __restrict__ csr,
    const float* __restrict__ bg, unsigned short* __restrict__ aggb,
    float* __restrict__ gates, float* __restrict__ imp, int* __restrict__ loadc) {
  __shared__ __align__(16) unsigned short stage[4][16 * DD];  // 8 KB per wave
  __shared__ float s_imp[NX];
  __shared__ int s_load[NX];
  int t = threadIdx.x;
  if (t < NX) { s_imp[t] = 0.f; s_load[t] = 0; }
  __syncthreads();
  int wv = t >> 6, lane = t & 63;
  int n = blockIdx.x * 4 + wv;  // 12500 blocks * 4 waves == 50000
  int i0 = rowptr[n], i1 = rowptr[n + 1];
  int cnt = i1 - i0;
  float4 a = make_float4(0.f, 0.f, 0.f, 0.f);
  float pg = 0.f;
  int jg = lane >> 3, eg = lane & 7;
  int half = lane >> 5, l31 = lane & 31;
  unsigned short* sbuf = &stage[wv][0];
  const unsigned short* srow = sbuf + lane * 4;  // this lane's 8B column slice

  for (int base = 0; base < cnt; base += 16) {
    int rem = cnt - base;
    if (rem > 16) rem = 16;
    int idx = 0;
    if (lane < rem) idx = csr[i0 + base + lane];  // lane l holds edge l's src

    // stage rem rows: 2 rows per instruction (lanes 0-31 / 32-63)
    int nins = (rem + 1) >> 1;
    for (int j = 0; j < nins; j++) {
      int ra = 2 * j, rb = 2 * j + 1;
      if (rb >= rem) rb = rem - 1;  // odd tail: duplicate last row (not consumed twice)
      int sA = __builtin_amdgcn_readlane(idx, ra);
      int sB = __builtin_amdgcn_readlane(idx, rb);
      int s = half ? sB : sA;
      const unsigned short* src = xb + ((size_t)s << 8) + l31 * 8;  // 16 B/lane
      __builtin_amdgcn_global_load_lds((const AS1 unsigned int*)src,
                                       (AS3 unsigned int*)(sbuf + j * 512), 16, 0, 0);
    }
    asm volatile("s_waitcnt vmcnt(0)" ::: "memory");
    __builtin_amdgcn_sched_barrier(0);

    // reduce staged rows in edge order (bit-identical to previous rounds)
    for (int j = 0; j < rem; j++) {
      ushort4 v = *(const ushort4*)(srow + j * 256);
      a.x += bf2f(v.x);
      a.y += bf2f(v.y);
      a.z += bf2f(v.z);
      a.w += bf2f(v.w);
    }
    // gate logits: exact prior pattern (order-preserving), 8 edges per step
    for (int i = 0; i < rem; i += 8) {
      int k = i + jg;
      int sk = __shfl(idx, k & 63, 64);
      float v = 0.f;
      if (k < rem) v = xg[((size_t)sk << 3) + eg];
      pg += v;
    }
  }

  // bf16 agg row for the expert GEMM
  ushort4 ab;
  ab.x = f2bf(a.x); ab.y = f2bf(a.y); ab.z = f2bf(a.z); ab.w = f2bf(a.w);
  ((ushort4*)aggb)[(size_t)n * 64 + lane] = ab;

  // reduce gate partials across jg slices
  pg += __shfl_xor(pg, 8, 64);
  pg += __shfl_xor(pg, 16, 64);
  pg += __shfl_xor(pg, 32, 64);

  float lg[NX];
#pragma unroll
  for (int e = 0; e < NX; e++) lg[e] = fmaxf(__shfl(pg, e, 64) + bg[e], 0.f);

  // top-3, lowest-index tie-break (matches stable lax.top_k)
  int ti0 = 0, ti1 = 0, ti2 = 0;
  float tv0 = -1.f, tv1 = -1.f, tv2 = -1.f;
#pragma unroll
  for (int e = 0; e < NX; e++) if (lg[e] > tv0) { tv0 = lg[e]; ti0 = e; }
#pragma unroll
  for (int e = 0; e < NX; e++) if (e != ti0 && lg[e] > tv1) { tv1 = lg[e]; ti1 = e; }
#pragma unroll
  for (int e = 0; e < NX; e++) if (e != ti0 && e != ti1 && lg[e] > tv2) { tv2 = lg[e]; ti2 = e; }

  float e1 = expf(tv1 - tv0), e2 = expf(tv2 - tv0);
  float inv = 1.f / (1.f + e1 + e2);
  float g0 = inv, g1 = e1 * inv, g2 = e2 * inv;

  if (lane == 0) {
    float go[NX];
#pragma unroll
    for (int e = 0; e < NX; e++)
      go[e] = (e == ti0) ? g0 : ((e == ti1) ? g1 : ((e == ti2) ? g2 : 0.f));
    float4* gp = (float4*)(gates + (size_t)n * NX);
    gp[0] = make_float4(go[0], go[1], go[2], go[3]);
    gp[1] = make_float4(go[4], go[5], go[6], go[7]);
    atomicAdd(&s_imp[ti0], g0); atomicAdd(&s_imp[ti1], g1); atomicAdd(&s_imp[ti2], g2);
    atomicAdd(&s_load[ti0], 1); atomicAdd(&s_load[ti1], 1); atomicAdd(&s_load[ti2], 1);
  }
  __syncthreads();
  if (t < NX) { atomicAdd(&imp[t], s_imp[t]); atomicAdd(&loadc[t], s_load[t]); }
}

// ---------------- experts: 128x128 tile, LDS-staged B, dbuf, swizzled; + aux loss ----------------
__global__ __launch_bounds__(256, 2) void k_y(
    const unsigned short* __restrict__ aggb, const unsigned short* __restrict__ Wt,
    const float* __restrict__ gates, const float* __restrict__ be,
    const float* __restrict__ imp, const int* __restrict__ loadc,
    float* __restrict__ y) {
  __shared__ __align__(16) unsigned short ldsB[2][BN * 128];  // 2 x 32 KB
  __shared__ float ldsg[BM][12];
  __shared__ float ldsb[NX][BN];
  int t = threadIdx.x;
  // aux loss: one thread of block 0
  if (blockIdx.x == 0 && t == 0) {
    double mi = 0, ml = 0;
    for (int e = 0; e < NX; e++) { mi += imp[e]; ml += (double)loadc[e]; }
    mi *= 0.125; ml *= 0.125;
    double vi = 0, vl = 0;
    for (int e = 0; e < NX; e++) {
      double di = imp[e] - mi, dl = (double)loadc[e] - ml;
      vi += di * di; vl += dl * dl;
    }
    vi /= 7.0; vl /= 7.0;  // ddof=1
    double cv = vi / (mi * mi + 1e-10) + vl / (ml * ml + 1e-10);
    y[(size_t)NN * DD] = (float)(0.01 * cv);
  }
  int rb = blockIdx.x >> 1, cb = blockIdx.x & 1;
  int r0 = rb * BM, c0 = cb * BN;
  int wv = t >> 6, l = t & 63, l15 = l & 15, lgp = l >> 4;

  auto stageB = [&](int e, int h, int buf) {
#pragma unroll
    for (int i = 0; i < 8; i++) {
      int c = (i * 4 + wv) * 4 + lgp;
      int d = ((l & 15) ^ (c & 7)) * 8;  // pre-swizzled source k-offset
      const unsigned short* gp = Wt + (((e << 8) + c0 + c) << 8) + (h << 7) + d;
      __builtin_amdgcn_global_load_lds((const AS1 unsigned int*)gp,
                                       (AS3 unsigned int*)&ldsB[buf][(i * 4 + wv) * 512],
                                       16, 0, 0);
    }
  };

  {
    int r = t >> 1, hf = t & 1;
    int gr = r0 + r;
    float4 gv = make_float4(0.f, 0.f, 0.f, 0.f);
    if (gr < NN) gv = ((const float4*)gates)[(size_t)gr * 2 + hf];
    ldsg[r][hf * 4 + 0] = gv.x; ldsg[r][hf * 4 + 1] = gv.y;
    ldsg[r][hf * 4 + 2] = gv.z; ldsg[r][hf * 4 + 3] = gv.w;
  }
  {
    int e = t >> 5, c = (t & 31) * 4;
    *(float4*)&ldsb[e][c] = *(const float4*)(be + (e << 8) + c0 + c);
  }

  s8v afr[2][8];
#pragma unroll
  for (int rf = 0; rf < 2; rf++) {
    int row = r0 + wv * 32 + rf * 16 + l15;
    if (row >= NN) row = NN - 1;  // clamp; gate==0 kills contribution
    const unsigned short* ap = aggb + ((size_t)row << 8) + lgp * 8;
#pragma unroll
    for (int ks = 0; ks < 8; ks++) afr[rf][ks] = *(const s8v*)(ap + ks * 32);
  }

  f4v yac[2][8];
#pragma unroll
  for (int rf = 0; rf < 2; rf++)
#pragma unroll
    for (int cf = 0; cf < 8; cf++) yac[rf][cf] = (f4v)0.0f;

  stageB(0, 0, 0);
  __syncthreads();

  for (int e = 0; e < NX; e++) {
    f4v ac[2][8];
#pragma unroll
    for (int rf = 0; rf < 2; rf++)
#pragma unroll
      for (int cf = 0; cf < 8; cf++) ac[rf][cf] = (f4v)0.0f;

#pragma unroll
    for (int h = 0; h < 2; h++) {
      if (h == 0) stageB(e, 1, 1);
      else if (e < 7) stageB(e + 1, 0, 0);
#pragma unroll
      for (int cf = 0; cf < 8; cf++) {
        int c = cf * 16 + l15;
#pragma unroll
        for (int ksl = 0; ksl < 4; ksl++) {
          int u = (ksl * 4 + lgp) ^ (c & 7);
          s8v b = *(const s8v*)&ldsB[h][c * 128 + u * 8];
          ac[0][cf] = __builtin_amdgcn_mfma_f32_16x16x32_bf16(afr[0][h * 4 + ksl], b, ac[0][cf], 0, 0, 0);
          ac[1][cf] = __builtin_amdgcn_mfma_f32_16x16x32_bf16(afr[1][h * 4 + ksl], b, ac[1][cf], 0, 0, 0);
        }
      }
      __syncthreads();
    }
#pragma unroll
    for (int rf = 0; rf < 2; rf++)
#pragma unroll
      for (int r = 0; r < 4; r++) {
        float g = ldsg[wv * 32 + rf * 16 + lgp * 4 + r][e];
#pragma unroll
        for (int cf = 0; cf < 8; cf++)
          yac[rf][cf][r] += g * (ac[rf][cf][r] + ldsb[e][cf * 16 + l15]);
      }
  }

#pragma unroll
  for (int rf = 0; rf < 2; rf++)
#pragma unroll
    for (int r = 0; r < 4; r++) {
      int row = r0 + wv * 32 + rf * 16 + lgp * 4 + r;
      if (row < NN) {
#pragma unroll
        for (int cf = 0; cf < 8; cf++)
          y[(size_t)row * DD + c0 + cf * 16 + l15] = yac[rf][cf][r];
      }
    }
}

extern "C" void kernel_launch(void* const* d_in, const int* in_sizes, int n_in,
                              void* d_out, int out_size, void* d_ws, size_t ws_size,
                              hipStream_t stream) {
  const float* x  = (const float*)d_in[0];
  const int*   ei = (const int*)d_in[1];
  const float* Wg = (const float*)d_in[2];
  const float* bg = (const float*)d_in[3];
  const float* We = (const float*)d_in[4];
  const float* be = (const float*)d_in[5];
  float* y = (float*)d_out;  // [NN*DD] then loss scalar at [NN*DD]

  char* w = (char*)d_ws;
  auto alloc = [&](size_t bytes) {
    char* p = w;
    w += (bytes + 255) & ~(size_t)255;
    return p;
  };
  unsigned short* aggb   = (unsigned short*)alloc((size_t)NN * DD * 2);
  unsigned short* xb     = (unsigned short*)alloc((size_t)NN * DD * 2);
  float*          xg     = (float*)alloc((size_t)NN * NX * 4);
  unsigned short* Wt     = (unsigned short*)alloc((size_t)NX * DD * DD * 2);
  float*          gates  = (float*)alloc((size_t)NN * NX * 4);
  int*            rowptr = (int*)alloc((size_t)(NN + 1) * 4);
  int*            cursor = (int*)alloc((size_t)NN * 4);
  int*            csr    = (int*)alloc((size_t)NE * 4);
  int*            deg    = (int*)alloc((size_t)NN * 4 + 64);  // deg | imp | loadc
  int*            bsum   = (int*)alloc(64 * 4);
  int*            boff   = (int*)alloc(64 * 4);
  float*          imp    = (float*)(deg + NN);
  int*            loadc  = deg + NN + 8;

  hipMemsetAsync(deg, 0, (size_t)NN * 4 + 64, stream);
  k_prep<<<2048 + 12500 + 3125, 256, 0, stream>>>(x, Wg, We, ei, Wt, xb, xg, deg);
  k_scan1<<<49, 1024, 0, stream>>>(deg, rowptr, bsum);
  k_scan2<<<1, 64, 0, stream>>>(bsum, boff, rowptr);
  k_scan3<<<49, 1024, 0, stream>>>(rowptr, boff, cursor);
  k_scatter<<<(NE + 255) / 256, 256, 0, stream>>>(ei, cursor, csr);
  k_agggate<<<NN / 4, 256, 0, stream>>>(xb, xg, rowptr, csr, bg, aggb, gates, imp, loadc);
  k_y<<<391 * 2, 256, 0, stream>>>(aggb, Wt, gates, be, imp, loadc, y);
}

// Round 6
// 443.228 us; speedup vs baseline: 1.4579x; 1.4579x over previous
//
#include <hip/hip_runtime.h>

#define NN 50000   // nodes
#define NE 800000  // edges
#define DD 256     // feature dim
#define NX 8       // experts
#define NB 12500   // agggate blocks (4 nodes each)
#define BM 128     // k_y rows per block
#define BN 128     // k_y cols per block

typedef short s8v __attribute__((ext_vector_type(8)));   // 8 x bf16 (as i16)
typedef float f4v __attribute__((ext_vector_type(4)));   // MFMA accumulator

#define AS1 __attribute__((address_space(1)))
#define AS3 __attribute__((address_space(3)))

static __device__ __forceinline__ unsigned short f2bf(float f) {
  unsigned u = __builtin_bit_cast(unsigned, f);
  u = (u + 0x7fffu + ((u >> 16) & 1u)) >> 16;  // RNE
  return (unsigned short)u;
}
static __device__ __forceinline__ float bf2f(unsigned short u) {
  return __builtin_bit_cast(float, (unsigned)u << 16);
}

// ---------------- fused prep: Wt transpose | x->bf16 + xg | deg histogram ----------------
// blocks [0,2048): Wt   [2048,14548): xb+xg   [14548,17673): deg
__global__ __launch_bounds__(256) void k_prep(
    const float* __restrict__ x, const float* __restrict__ Wg,
    const float* __restrict__ We, const int* __restrict__ ei,
    unsigned short* __restrict__ Wt, unsigned short* __restrict__ xb,
    float* __restrict__ xg, int* __restrict__ deg) {
  int b = blockIdx.x, t = threadIdx.x;
  if (b < 2048) {  // Wt[e][o][d] = bf16(We[e][d][o])
    int i = b * 256 + t;
    int e = i >> 16, rem = i & 0xffff, o = rem >> 8, d = rem & 255;
    Wt[i] = f2bf(We[(e << 16) + (d << 8) + o]);
  } else if (b < 14548) {  // xb = bf16(x); xg = x @ Wg (f32)
    int wv = t >> 6, lane = t & 63;
    int n = (b - 2048) * 4 + wv;
    float4 v = ((const float4*)x)[(size_t)n * 64 + lane];
    ushort4 bb;
    bb.x = f2bf(v.x); bb.y = f2bf(v.y); bb.z = f2bf(v.z); bb.w = f2bf(v.w);
    ((ushort4*)xb)[(size_t)n * 64 + lane] = bb;
    float p[NX];
#pragma unroll
    for (int e = 0; e < NX; e++) p[e] = 0.f;
    const float* wr = Wg + lane * 4 * NX;
    float av[4] = {v.x, v.y, v.z, v.w};
#pragma unroll
    for (int j = 0; j < 4; j++)
#pragma unroll
      for (int e = 0; e < NX; e++) p[e] = fmaf(av[j], wr[j * NX + e], p[e]);
#pragma unroll
    for (int off = 32; off > 0; off >>= 1)
#pragma unroll
      for (int e = 0; e < NX; e++) p[e] += __shfl_xor(p[e], off, 64);
    if (lane == 0) {
      float4* gp = (float4*)(xg + (size_t)n * NX);
      gp[0] = make_float4(p[0], p[1], p[2], p[3]);
      gp[1] = make_float4(p[4], p[5], p[6], p[7]);
    }
  } else {  // degree histogram over dst
    int e = (b - 14548) * 256 + t;
    if (e < NE) atomicAdd(&deg[ei[NE + e]], 1);
  }
}

// 49 blocks x 1024: per-block exclusive scan -> rowptr, block totals -> bsum
__global__ void k_scan1(const int* __restrict__ deg, int* __restrict__ rowptr,
                        int* __restrict__ bsum) {
  __shared__ int buf[2][1024];
  int t = threadIdx.x, base = blockIdx.x * 1024;
  int v = (base + t < NN) ? deg[base + t] : 0;
  buf[0][t] = v;
  int cur = 0;
  __syncthreads();
  for (int off = 1; off < 1024; off <<= 1) {
    int s = buf[cur][t];
    if (t >= off) s += buf[cur][t - off];
    buf[cur ^ 1][t] = s;
    cur ^= 1;
    __syncthreads();
  }
  if (base + t < NN) rowptr[base + t] = buf[cur][t] - v;
  if (t == 1023) bsum[blockIdx.x] = buf[cur][1023];
}

__global__ void k_scan2(const int* __restrict__ bsum, int* __restrict__ boff,
                        int* __restrict__ rowptr) {
  int l = threadIdx.x;
  int v = (l < 49) ? bsum[l] : 0;
  int s = v;
  for (int off = 1; off < 64; off <<= 1) {
    int o = __shfl_up(s, off, 64);
    if (l >= off) s += o;
  }
  if (l < 49) boff[l] = s - v;
  if (l == 0) rowptr[NN] = NE;
}

__global__ void k_scan3(int* __restrict__ rowptr, const int* __restrict__ boff,
                        int* __restrict__ cursor) {
  int i = blockIdx.x * 1024 + threadIdx.x;
  if (i < NN) {
    int r = rowptr[i] + boff[blockIdx.x];
    rowptr[i] = r;
    cursor[i] = r;
  }
}

__global__ void k_scatter(const int* __restrict__ ei, int* __restrict__ cursor,
                          int* __restrict__ csr) {
  int e = blockIdx.x * 256 + threadIdx.x;
  if (e < NE) {
    int s = ei[e];
    int d = ei[NE + e];
    int p = atomicAdd(&cursor[d], 1);
    csr[p] = s;
  }
}

// ---------------- fused aggregation + gate: LDS-staged gather; NO global atomics ----------------
// Per-block importance/load partials go to pimp/pload slots (plain stores);
// k_red reduces them. (Global same-line atomics were a ~300us serialization wall.)
__global__ __launch_bounds__(256) void k_agggate(
    const unsigned short* __restrict__ xb, const float* __restrict__ xg,
    const int* __restrict__ rowptr, const int* __restrict__ csr,
    const float* __restrict__ bg, unsigned short* __restrict__ aggb,
    float* __restrict__ gates, float* __restrict__ pimp, int* __restrict__ pload) {
  __shared__ __align__(16) unsigned short stage[4][16 * DD];  // 8 KB per wave
  __shared__ float s_imp[NX];
  __shared__ int s_load[NX];
  int t = threadIdx.x;
  if (t < NX) { s_imp[t] = 0.f; s_load[t] = 0; }
  __syncthreads();
  int wv = t >> 6, lane = t & 63;
  int n = blockIdx.x * 4 + wv;  // 12500 blocks * 4 waves == 50000
  int i0 = rowptr[n], i1 = rowptr[n + 1];
  int cnt = i1 - i0;
  float4 a = make_float4(0.f, 0.f, 0.f, 0.f);
  float pg = 0.f;
  int jg = lane >> 3, eg = lane & 7;
  int half = lane >> 5, l31 = lane & 31;
  unsigned short* sbuf = &stage[wv][0];
  const unsigned short* srow = sbuf + lane * 4;  // this lane's 8B column slice

  for (int base = 0; base < cnt; base += 16) {
    int rem = cnt - base;
    if (rem > 16) rem = 16;
    int idx = 0;
    if (lane < rem) idx = csr[i0 + base + lane];  // lane l holds edge l's src

    // stage rem rows: 2 rows per instruction (lanes 0-31 / 32-63)
    int nins = (rem + 1) >> 1;
    for (int j = 0; j < nins; j++) {
      int ra = 2 * j, rb = 2 * j + 1;
      if (rb >= rem) rb = rem - 1;  // odd tail: duplicate last row (not consumed twice)
      int sA = __builtin_amdgcn_readlane(idx, ra);
      int sB = __builtin_amdgcn_readlane(idx, rb);
      int s = half ? sB : sA;
      const unsigned short* src = xb + ((size_t)s << 8) + l31 * 8;  // 16 B/lane
      __builtin_amdgcn_global_load_lds((const AS1 unsigned int*)src,
                                       (AS3 unsigned int*)(sbuf + j * 512), 16, 0, 0);
    }
    asm volatile("s_waitcnt vmcnt(0)" ::: "memory");
    __builtin_amdgcn_sched_barrier(0);

    // reduce staged rows in edge order (bit-identical to previous rounds)
    for (int j = 0; j < rem; j++) {
      ushort4 v = *(const ushort4*)(srow + j * 256);
      a.x += bf2f(v.x);
      a.y += bf2f(v.y);
      a.z += bf2f(v.z);
      a.w += bf2f(v.w);
    }
    // gate logits: exact prior pattern (order-preserving), 8 edges per step
    for (int i = 0; i < rem; i += 8) {
      int k = i + jg;
      int sk = __shfl(idx, k & 63, 64);
      float v = 0.f;
      if (k < rem) v = xg[((size_t)sk << 3) + eg];
      pg += v;
    }
  }

  // bf16 agg row for the expert GEMM
  ushort4 ab;
  ab.x = f2bf(a.x); ab.y = f2bf(a.y); ab.z = f2bf(a.z); ab.w = f2bf(a.w);
  ((ushort4*)aggb)[(size_t)n * 64 + lane] = ab;

  // reduce gate partials across jg slices
  pg += __shfl_xor(pg, 8, 64);
  pg += __shfl_xor(pg, 16, 64);
  pg += __shfl_xor(pg, 32, 64);

  float lg[NX];
#pragma unroll
  for (int e = 0; e < NX; e++) lg[e] = fmaxf(__shfl(pg, e, 64) + bg[e], 0.f);

  // top-3, lowest-index tie-break (matches stable lax.top_k)
  int ti0 = 0, ti1 = 0, ti2 = 0;
  float tv0 = -1.f, tv1 = -1.f, tv2 = -1.f;
#pragma unroll
  for (int e = 0; e < NX; e++) if (lg[e] > tv0) { tv0 = lg[e]; ti0 = e; }
#pragma unroll
  for (int e = 0; e < NX; e++) if (e != ti0 && lg[e] > tv1) { tv1 = lg[e]; ti1 = e; }
#pragma unroll
  for (int e = 0; e < NX; e++) if (e != ti0 && e != ti1 && lg[e] > tv2) { tv2 = lg[e]; ti2 = e; }

  float e1 = expf(tv1 - tv0), e2 = expf(tv2 - tv0);
  float inv = 1.f / (1.f + e1 + e2);
  float g0 = inv, g1 = e1 * inv, g2 = e2 * inv;

  if (lane == 0) {
    float go[NX];
#pragma unroll
    for (int e = 0; e < NX; e++)
      go[e] = (e == ti0) ? g0 : ((e == ti1) ? g1 : ((e == ti2) ? g2 : 0.f));
    float4* gp = (float4*)(gates + (size_t)n * NX);
    gp[0] = make_float4(go[0], go[1], go[2], go[3]);
    gp[1] = make_float4(go[4], go[5], go[6], go[7]);
    atomicAdd(&s_imp[ti0], g0); atomicAdd(&s_imp[ti1], g1); atomicAdd(&s_imp[ti2], g2);
    atomicAdd(&s_load[ti0], 1); atomicAdd(&s_load[ti1], 1); atomicAdd(&s_load[ti2], 1);
  }
  __syncthreads();
  if (t < NX) {  // plain stores to this block's private slot — no contention
    pimp[blockIdx.x * NX + t] = s_imp[t];
    pload[blockIdx.x * NX + t] = s_load[t];
  }
}

// ---------------- reduce partials + aux loss ----------------
__global__ __launch_bounds__(1024) void k_red(
    const float* __restrict__ pimp, const int* __restrict__ pload,
    float* __restrict__ out) {
  __shared__ float ri[128][NX];
  __shared__ int rl[128][NX];
  int t = threadIdx.x;
  int e = t & 7, g = t >> 3;  // g in [0,128)
  float si = 0.f;
  int sl = 0;
  for (int r = g; r < NB; r += 128) {
    si += pimp[r * NX + e];
    sl += pload[r * NX + e];
  }
  ri[g][e] = si;
  rl[g][e] = sl;
  __syncthreads();
  if (t < NX) {
    float a = 0.f;
    int b = 0;
    for (int g2 = 0; g2 < 128; g2++) { a += ri[g2][t]; b += rl[g2][t]; }
    ri[0][t] = a;
    rl[0][t] = b;
  }
  __syncthreads();
  if (t == 0) {
    double mi = 0, ml = 0;
    for (int e2 = 0; e2 < NX; e2++) { mi += ri[0][e2]; ml += (double)rl[0][e2]; }
    mi *= 0.125; ml *= 0.125;
    double vi = 0, vl = 0;
    for (int e2 = 0; e2 < NX; e2++) {
      double di = ri[0][e2] - mi, dl = (double)rl[0][e2] - ml;
      vi += di * di; vl += dl * dl;
    }
    vi /= 7.0; vl /= 7.0;  // ddof=1
    double cv = vi / (mi * mi + 1e-10) + vl / (ml * ml + 1e-10);
    out[0] = (float)(0.01 * cv);
  }
}

// ---------------- experts: 128x128 tile, LDS-staged B, dbuf, swizzled ----------------
__global__ __launch_bounds__(256, 2) void k_y(
    const unsigned short* __restrict__ aggb, const unsigned short* __restrict__ Wt,
    const float* __restrict__ gates, const float* __restrict__ be,
    float* __restrict__ y) {
  __shared__ __align__(16) unsigned short ldsB[2][BN * 128];  // 2 x 32 KB
  __shared__ float ldsg[BM][12];
  __shared__ float ldsb[NX][BN];
  int t = threadIdx.x;
  int rb = blockIdx.x >> 1, cb = blockIdx.x & 1;
  int r0 = rb * BM, c0 = cb * BN;
  int wv = t >> 6, l = t & 63, l15 = l & 15, lgp = l >> 4;

  auto stageB = [&](int e, int h, int buf) {
#pragma unroll
    for (int i = 0; i < 8; i++) {
      int c = (i * 4 + wv) * 4 + lgp;
      int d = ((l & 15) ^ (c & 7)) * 8;  // pre-swizzled source k-offset
      const unsigned short* gp = Wt + (((e << 8) + c0 + c) << 8) + (h << 7) + d;
      __builtin_amdgcn_global_load_lds((const AS1 unsigned int*)gp,
                                       (AS3 unsigned int*)&ldsB[buf][(i * 4 + wv) * 512],
                                       16, 0, 0);
    }
  };

  {
    int r = t >> 1, hf = t & 1;
    int gr = r0 + r;
    float4 gv = make_float4(0.f, 0.f, 0.f, 0.f);
    if (gr < NN) gv = ((const float4*)gates)[(size_t)gr * 2 + hf];
    ldsg[r][hf * 4 + 0] = gv.x; ldsg[r][hf * 4 + 1] = gv.y;
    ldsg[r][hf * 4 + 2] = gv.z; ldsg[r][hf * 4 + 3] = gv.w;
  }
  {
    int e = t >> 5, c = (t & 31) * 4;
    *(float4*)&ldsb[e][c] = *(const float4*)(be + (e << 8) + c0 + c);
  }

  s8v afr[2][8];
#pragma unroll
  for (int rf = 0; rf < 2; rf++) {
    int row = r0 + wv * 32 + rf * 16 + l15;
    if (row >= NN) row = NN - 1;  // clamp; gate==0 kills contribution
    const unsigned short* ap = aggb + ((size_t)row << 8) + lgp * 8;
#pragma unroll
    for (int ks = 0; ks < 8; ks++) afr[rf][ks] = *(const s8v*)(ap + ks * 32);
  }

  f4v yac[2][8];
#pragma unroll
  for (int rf = 0; rf < 2; rf++)
#pragma unroll
    for (int cf = 0; cf < 8; cf++) yac[rf][cf] = (f4v)0.0f;

  stageB(0, 0, 0);
  __syncthreads();

  for (int e = 0; e < NX; e++) {
    f4v ac[2][8];
#pragma unroll
    for (int rf = 0; rf < 2; rf++)
#pragma unroll
      for (int cf = 0; cf < 8; cf++) ac[rf][cf] = (f4v)0.0f;

#pragma unroll
    for (int h = 0; h < 2; h++) {
      if (h == 0) stageB(e, 1, 1);
      else if (e < 7) stageB(e + 1, 0, 0);
#pragma unroll
      for (int cf = 0; cf < 8; cf++) {
        int c = cf * 16 + l15;
#pragma unroll
        for (int ksl = 0; ksl < 4; ksl++) {
          int u = (ksl * 4 + lgp) ^ (c & 7);
          s8v b = *(const s8v*)&ldsB[h][c * 128 + u * 8];
          ac[0][cf] = __builtin_amdgcn_mfma_f32_16x16x32_bf16(afr[0][h * 4 + ksl], b, ac[0][cf], 0, 0, 0);
          ac[1][cf] = __builtin_amdgcn_mfma_f32_16x16x32_bf16(afr[1][h * 4 + ksl], b, ac[1][cf], 0, 0, 0);
        }
      }
      __syncthreads();
    }
#pragma unroll
    for (int rf = 0; rf < 2; rf++)
#pragma unroll
      for (int r = 0; r < 4; r++) {
        float g = ldsg[wv * 32 + rf * 16 + lgp * 4 + r][e];
#pragma unroll
        for (int cf = 0; cf < 8; cf++)
          yac[rf][cf][r] += g * (ac[rf][cf][r] + ldsb[e][cf * 16 + l15]);
      }
  }

#pragma unroll
  for (int rf = 0; rf < 2; rf++)
#pragma unroll
    for (int r = 0; r < 4; r++) {
      int row = r0 + wv * 32 + rf * 16 + lgp * 4 + r;
      if (row < NN) {
#pragma unroll
        for (int cf = 0; cf < 8; cf++)
          y[(size_t)row * DD + c0 + cf * 16 + l15] = yac[rf][cf][r];
      }
    }
}

extern "C" void kernel_launch(void* const* d_in, const int* in_sizes, int n_in,
                              void* d_out, int out_size, void* d_ws, size_t ws_size,
                              hipStream_t stream) {
  const float* x  = (const float*)d_in[0];
  const int*   ei = (const int*)d_in[1];
  const float* Wg = (const float*)d_in[2];
  const float* bg = (const float*)d_in[3];
  const float* We = (const float*)d_in[4];
  const float* be = (const float*)d_in[5];
  float* y = (float*)d_out;  // [NN*DD] then loss scalar at [NN*DD]

  char* w = (char*)d_ws;
  auto alloc = [&](size_t bytes) {
    char* p = w;
    w += (bytes + 255) & ~(size_t)255;
    return p;
  };
  unsigned short* aggb   = (unsigned short*)alloc((size_t)NN * DD * 2);
  unsigned short* xb     = (unsigned short*)alloc((size_t)NN * DD * 2);
  float*          xg     = (float*)alloc((size_t)NN * NX * 4);
  unsigned short* Wt     = (unsigned short*)alloc((size_t)NX * DD * DD * 2);
  float*          gates  = (float*)alloc((size_t)NN * NX * 4);
  int*            rowptr = (int*)alloc((size_t)(NN + 1) * 4);
  int*            cursor = (int*)alloc((size_t)NN * 4);
  int*            csr    = (int*)alloc((size_t)NE * 4);
  int*            deg    = (int*)alloc((size_t)NN * 4);
  float*          pimp   = (float*)alloc((size_t)NB * NX * 4);
  int*            pload  = (int*)alloc((size_t)NB * NX * 4);
  int*            bsum   = (int*)alloc(64 * 4);
  int*            boff   = (int*)alloc(64 * 4);

  hipMemsetAsync(deg, 0, (size_t)NN * 4, stream);
  k_prep<<<2048 + 12500 + 3125, 256, 0, stream>>>(x, Wg, We, ei, Wt, xb, xg, deg);
  k_scan1<<<49, 1024, 0, stream>>>(deg, rowptr, bsum);
  k_scan2<<<1, 64, 0, stream>>>(bsum, boff, rowptr);
  k_scan3<<<49, 1024, 0, stream>>>(rowptr, boff, cursor);
  k_scatter<<<(NE + 255) / 256, 256, 0, stream>>>(ei, cursor, csr);
  k_agggate<<<NB, 256, 0, stream>>>(xb, xg, rowptr, csr, bg, aggb, gates, pimp, pload);
  k_red<<<1, 1024, 0, stream>>>(pimp, pload, y + (size_t)NN * DD);
  k_y<<<391 * 2, 256, 0, stream>>>(aggb, Wt, gates, be, y);
}